// Round 1
// baseline (140.408 us; speedup 1.0000x reference)
//
#include <hip/hip_runtime.h>
#include <cfloat>

#define BB 8
#define CCH 64
#define HH 128
#define WW 128
#define HW (HH * WW)
#define NUM 32
#define PLANES (BB * CCH)
#define CAND_CAP 2176
#define NTHREADS 256

// f64 window-sum at (i,j) with zero padding, fixed summation order
// (row-wise 3-sums left-to-right, then vertical top-to-bottom).
__device__ double ws_at(const float* xpl, int i, int j) {
    double h[3];
    for (int d = -1; d <= 1; ++d) {
        int r = i + d;
        double a = 0.0, b = 0.0, c = 0.0;
        if (r >= 0 && r < HH) {
            const float* row = xpl + r * WW;
            a = (j - 1 >= 0) ? (double)row[j - 1] : 0.0;
            b = (double)row[j];
            c = (j + 1 < WW) ? (double)row[j + 1] : 0.0;
        }
        h[d + 1] = a + b + c;
    }
    return h[0] + h[1] + h[2];
}

__device__ bool is_peak(const float* xpl, int i, int j) {
    double v = ws_at(xpl, i, j);
    for (int di = -1; di <= 1; ++di)
        for (int dj = -1; dj <= 1; ++dj) {
            if (di == 0 && dj == 0) continue;
            int r = i + di, c = j + dj;
            if (r < 0 || r >= HH || c < 0 || c >= WW) continue;
            if (ws_at(xpl, r, c) > v) return false;
        }
    return true;
}

__device__ __forceinline__ bool better(double av, int ai, double bv, int bi) {
    // "better" = ranks earlier in top_k output: larger value, then smaller index
    return (av > bv) || (av == bv && ai < bi);
}

__global__ __launch_bounds__(NTHREADS) void nms_kernel(const float* __restrict__ x,
                                                       float* __restrict__ out) {
    const int p = blockIdx.x;
    const float* xpl = x + (size_t)p * HW;
    const int tid = threadIdx.x;
    const int lane = tid & 63;
    const int wid = tid >> 6;

    __shared__ float xs[68 * 128];            // 34816 B
    __shared__ double cand_val[CAND_CAP];     // 17408 B
    __shared__ int cand_idx[CAND_CAP];        //  8704 B
    __shared__ int cand_cnt;
    __shared__ double topk_val[NUM];
    __shared__ int topk_idx[NUM];
    __shared__ int nsel;
    __shared__ double red_val[4];
    __shared__ int red_idx[4];
    __shared__ int gbest_idx;
    __shared__ int sel_idx[NUM];

    if (tid == 0) nsel = 0;

    const int j = tid & 127;   // column owned by this thread
    const int s = tid >> 7;    // row-subgroup (0/1)

    for (int half = 0; half < 2; ++half) {
        const int base_row = half * 64 - 2;  // global row of xs row 0
        __syncthreads();
        if (tid == 0) cand_cnt = 0;
        // stage rows base_row .. base_row+67 (zeros outside [0,128))
        for (int k = tid; k < 68 * 32; k += NTHREADS) {
            int rr = k >> 5, c4 = (k & 31) << 2;
            int gr = base_row + rr;
            float4 v = make_float4(0.f, 0.f, 0.f, 0.f);
            if (gr >= 0 && gr < HH) v = *(const float4*)(xpl + gr * WW + c4);
            *(float4*)(&xs[rr * 128 + c4]) = v;
        }
        __syncthreads();

        const int i0 = half * 64 + s * 32;  // first peak row for this thread

        // horizontal 3-sum triplet for columns j-1,j,j+1 at global row r
        auto HS3 = [&](int r, double h[3]) {
            const float* row = &xs[(r - base_row) * 128];
            double a = (j >= 2) ? (double)row[j - 2] : 0.0;
            double b = (j >= 1) ? (double)row[j - 1] : 0.0;
            double c = (double)row[j];
            double d = (j <= 126) ? (double)row[j + 1] : 0.0;
            double e = (j <= 125) ? (double)row[j + 2] : 0.0;
            h[0] = a + b + c;
            h[1] = b + c + d;
            h[2] = c + d + e;
        };

        double hA[3], hB[3], hC[3];
        double wm[3], wc[3], wn[3];
        {
            double h0[3], h1[3];
            HS3(i0 - 2, h0);
            HS3(i0 - 1, h1);
            HS3(i0, hA);
            HS3(i0 + 1, hB);
            if (i0 - 1 >= 0) {
                wm[0] = h0[0] + h1[0] + hA[0];
                wm[1] = h0[1] + h1[1] + hA[1];
                wm[2] = h0[2] + h1[2] + hA[2];
            } else {
                wm[0] = wm[1] = wm[2] = -DBL_MAX;  // max-pool -inf pad
            }
            wc[0] = h1[0] + hA[0] + hB[0];
            wc[1] = h1[1] + hA[1] + hB[1];
            wc[2] = h1[2] + hA[2] + hB[2];
        }
        for (int i = i0; i < i0 + 32; ++i) {
            HS3(i + 2, hC);
            if (i + 1 < HH) {
                wn[0] = hA[0] + hB[0] + hC[0];
                wn[1] = hA[1] + hB[1] + hC[1];
                wn[2] = hA[2] + hB[2] + hC[2];
            } else {
                wn[0] = wn[1] = wn[2] = -DBL_MAX;
            }
            double v = wc[1];
            bool pk = (v >= wm[1]) && (v >= wn[1]);
            if (j > 0)   pk = pk && (v >= wm[0]) && (v >= wc[0]) && (v >= wn[0]);
            if (j < 127) pk = pk && (v >= wm[2]) && (v >= wc[2]) && (v >= wn[2]);
            if (pk) {
                int pos = atomicAdd(&cand_cnt, 1);
                if (pos < CAND_CAP) { cand_val[pos] = v; cand_idx[pos] = i * WW + j; }
            }
            wm[0] = wc[0]; wm[1] = wc[1]; wm[2] = wc[2];
            wc[0] = wn[0]; wc[1] = wn[1]; wc[2] = wn[2];
            hA[0] = hB[0]; hA[1] = hB[1]; hA[2] = hB[2];
            hB[0] = hC[0]; hB[1] = hC[1]; hB[2] = hC[2];
        }
        __syncthreads();

        // merge previously-selected topk into candidate pool, reset selection
        if (tid == 0) {
            int n = nsel;
            for (int t = 0; t < n; ++t) {
                int pos = cand_cnt++;
                if (pos < CAND_CAP) { cand_val[pos] = topk_val[t]; cand_idx[pos] = topk_idx[t]; }
            }
            nsel = 0;
        }
        __syncthreads();
        const int P = min(cand_cnt, CAND_CAP);

        for (int round = 0; round < NUM; ++round) {
            double bv = -DBL_MAX;
            int bi_ = 0x7FFFFFFF;
            for (int i = tid; i < P; i += NTHREADS) {
                double v = cand_val[i];
                int ix = cand_idx[i];
                if (better(v, ix, bv, bi_)) { bv = v; bi_ = ix; }
            }
            for (int off = 32; off > 0; off >>= 1) {
                double ov = __shfl_down(bv, off);
                int oi = __shfl_down(bi_, off);
                if (better(ov, oi, bv, bi_)) { bv = ov; bi_ = oi; }
            }
            if (lane == 0) { red_val[wid] = bv; red_idx[wid] = bi_; }
            __syncthreads();
            if (tid == 0) {
                double gv = red_val[0];
                int gi = red_idx[0];
                for (int wv = 1; wv < 4; ++wv)
                    if (better(red_val[wv], red_idx[wv], gv, gi)) { gv = red_val[wv]; gi = red_idx[wv]; }
                if (gv > 0.0) {  // only strictly-positive peaks beat the zero pool
                    topk_val[nsel] = gv;
                    topk_idx[nsel] = gi;
                    nsel++;
                    gbest_idx = gi;
                } else {
                    gbest_idx = -1;
                }
            }
            __syncthreads();
            if (gbest_idx < 0) break;
            {
                const int gi = gbest_idx;
                for (int i = tid; i < P; i += NTHREADS)
                    if (cand_idx[i] == gi) { cand_val[i] = -DBL_MAX; cand_idx[i] = 0x7FFFFFFF; }
            }
            __syncthreads();
        }
    }

    __syncthreads();
    const int S = nsel;
    if (tid < NUM && tid < S) sel_idx[tid] = topk_idx[tid];
    __syncthreads();
    // Degenerate fallback (<32 strictly-positive peaks): fill with smallest
    // indices whose masked value is exactly 0 (ties in top_k go index-asc).
    if (tid == 0 && S < NUM) {
        int fill = S;
        for (int idx = 0; idx < HW && fill < NUM; ++idx) {
            int ii = idx >> 7, jj = idx & 127;
            double v = ws_at(xpl, ii, jj);
            bool zp = !(is_peak(xpl, ii, jj) && v != 0.0);
            if (zp) sel_idx[fill++] = idx;
        }
    }
    __syncthreads();

    if (tid < NUM) {
        const int idx = sel_idx[tid];
        const int h = idx >> 7, w = idx & 127;
        float* o0 = out + ((size_t)p * NUM + tid) * 9;
        for (int dr = 0; dr < 3; ++dr)
            for (int dc = 0; dc < 3; ++dc) {
                int rr = h - 1 + dr, cc = w - 1 + dc;
                float v = 0.f;
                if (rr >= 0 && rr < HH && cc >= 0 && cc < WW) v = xpl[rr * WW + cc];
                o0[dr * 3 + dc] = v;
            }
        float* o1 = out + (size_t)PLANES * NUM * 9 + ((size_t)p * NUM + tid) * 4;
        int x1 = max(w - 1, 0), y1 = max(h - 1, 0);
        int x2 = min(w + 1, WW - 1), y2 = min(h + 1, HH - 1);
        o1[0] = (float)x1;
        o1[1] = (float)y1;
        o1[2] = (float)x2;
        o1[3] = (float)y2;
    }
}

extern "C" void kernel_launch(void* const* d_in, const int* in_sizes, int n_in,
                              void* d_out, int out_size, void* d_ws, size_t ws_size,
                              hipStream_t stream) {
    const float* x = (const float*)d_in[0];
    float* out = (float*)d_out;
    (void)in_sizes; (void)n_in; (void)out_size; (void)d_ws; (void)ws_size;
    nms_kernel<<<PLANES, NTHREADS, 0, stream>>>(x, out);
}